// Round 3
// baseline (244.294 us; speedup 1.0000x reference)
//
#include <hip/hip_runtime.h>

// Problem dims (hardcoded from reference)
#define T_STEPS 256
#define B_ROWS  16384
#define IN_DIM  1024
#define C_CLS   10

typedef float vfloat4 __attribute__((ext_vector_type(4)));

// ---------------------------------------------------------------------------
// Fused kernel: per block (256 thr, 4 waves), 16 rows of x.
// Phase 1 (gemv): wave w computes rows w*4..w*4+3 over K=1024 (R1 structure:
//   full-wave 1KB coalesced x loads; W 40KB L1-resident, 40 loads/thread).
//   Reduction: xor-32/16 per acc (all lanes then hold their 4-lane-group
//   partial), pack the 4 row-accs into lane quarters via cndmask, then only
//   4 more xor steps on 10 packed regs. 120 shuffles vs 240.
// Phase 2 (expand): xw (160 floats) in LDS; thread's 10 float4 depend only on
//   tid&3 -> load once to regs; thread owns timestep t = tc*64 + tid/4 and
//   writes 10 float4; per wave-instr: 16 chunks x 64B (full lines).
//   coef(t) = 5 - 9*0.9^(t+1) + 4*0.8^(t+1)  (closed form of the LI scan).
// ---------------------------------------------------------------------------
__global__ __launch_bounds__(256) void fused_kernel(
    const float4* __restrict__ x4,   // [B][256] float4 view of x
    const float4* __restrict__ W4,   // [C][256] float4 view of W
    float4* __restrict__ out4)       // [T][B*C/4]
{
    __shared__ __align__(16) float sm[16 * C_CLS];   // xw for block's 16 rows

    const int tid  = threadIdx.x;
    const int wave = tid >> 6;
    const int lane = tid & 63;
    const int sub  = lane >> 4;       // lane quarter index 0..3
    const int row_base = blockIdx.x * 16 + wave * 4;

    // ---- Phase 1: xw = x @ W^T for 4 rows per wave ----
    float acc[4][C_CLS];
#pragma unroll
    for (int r = 0; r < 4; ++r)
#pragma unroll
        for (int c = 0; c < C_CLS; ++c) acc[r][c] = 0.0f;

#pragma unroll
    for (int p = 0; p < 4; ++p) {
        float4 w[C_CLS];
#pragma unroll
        for (int c = 0; c < C_CLS; ++c)
            w[c] = W4[c * 256 + p * 64 + lane];

#pragma unroll
        for (int r = 0; r < 4; ++r) {
            float4 xv = x4[(size_t)(row_base + r) * 256 + p * 64 + lane];
#pragma unroll
            for (int c = 0; c < C_CLS; ++c) {
                acc[r][c] = fmaf(xv.x, w[c].x,
                            fmaf(xv.y, w[c].y,
                            fmaf(xv.z, w[c].z,
                            fmaf(xv.w, w[c].w, acc[r][c]))));
            }
        }
    }

    // reduction tail: 2 butterfly steps per acc, quarter-pack, 4 more steps
#pragma unroll
    for (int c = 0; c < C_CLS; ++c) {
#pragma unroll
        for (int r = 0; r < 4; ++r) {
            acc[r][c] += __shfl_xor(acc[r][c], 32, 64);
            acc[r][c] += __shfl_xor(acc[r][c], 16, 64);
        }
        // every lane now holds the partial of its 4-lane group {l,l^16,l^32,l^48}
        float p = (sub < 2) ? (sub == 0 ? acc[0][c] : acc[1][c])
                            : (sub == 2 ? acc[2][c] : acc[3][c]);
        p += __shfl_xor(p, 8, 64);
        p += __shfl_xor(p, 4, 64);
        p += __shfl_xor(p, 2, 64);
        p += __shfl_xor(p, 1, 64);
        // lane 16*q holds the full dot product for row (wave*4+q), class c
        if ((lane & 15) == 0)
            sm[(wave * 4 + sub) * C_CLS + c] = p;
    }
    __syncthreads();

    // ---- Phase 2: out[t, b_block, :] = coef(t) * xw ----
    const float4* sm4 = (const float4*)sm;   // 40 float4
    float4 xwf[C_CLS];
#pragma unroll
    for (int j = 0; j < C_CLS; ++j)
        xwf[j] = sm4[(tid & 3) + 4 * j];

    const float L9 = -0.15200309344504995f;  // log2(0.9)
    const float L8 = -0.32192809488736235f;  // log2(0.8)
    const int   SLICE4 = (B_ROWS * C_CLS) / 4;          // 40960
    const size_t col = (size_t)blockIdx.x * 40 + (tid & 3);
    const int tq = tid >> 2;                  // 0..63

#pragma unroll
    for (int tc = 0; tc < 4; ++tc) {
        const int t = tc * 64 + tq;
        const float t1 = (float)(t + 1);
        const float coef = fmaf(-9.0f, exp2f(t1 * L9),
                           fmaf(4.0f, exp2f(t1 * L8), 5.0f));
        float4* dst = out4 + (size_t)t * SLICE4 + col;
#pragma unroll
        for (int j = 0; j < C_CLS; ++j) {
            vfloat4 o;
            o.x = xwf[j].x * coef; o.y = xwf[j].y * coef;
            o.z = xwf[j].z * coef; o.w = xwf[j].w * coef;
            __builtin_nontemporal_store(o, (vfloat4*)(dst + 4 * j));
        }
    }
}

extern "C" void kernel_launch(void* const* d_in, const int* in_sizes, int n_in,
                              void* d_out, int out_size, void* d_ws, size_t ws_size,
                              hipStream_t stream) {
    const float* x = (const float*)d_in[0];   // [B, IN] f32
    const float* W = (const float*)d_in[1];   // [C, IN] f32
    float* out = (float*)d_out;               // [T, B, C] f32

    fused_kernel<<<B_ROWS / 16, 256, 0, stream>>>(
        (const float4*)x, (const float4*)W, (float4*)out);
}

// Round 5
// 218.839 us; speedup vs baseline: 1.1163x; 1.1163x over previous
//
#include <hip/hip_runtime.h>

// Problem dims (hardcoded from reference)
#define T_STEPS 256
#define B_ROWS  16384
#define IN_DIM  1024
#define C_CLS   10

typedef float vfloat4 __attribute__((ext_vector_type(4)));

// ---------------------------------------------------------------------------
// Kernel 1: xw = x @ W^T   ([B,IN] @ [C,IN]^T -> [B,C])
// R1 structure (measured best): 1024 blocks x 4 waves; wave w owns rows
// w*4..w*4+3; full-wave float4 x loads (1 KB/instr, nontemporal - x is
// streamed once); W 40 KB, 40 loads/thread, L2-resident.
// R3's verified reduction tail: xor-32/16 per acc, pack 4 row-accs into lane
// quarters (selects, no shuffle), 4 more xor steps -> 120 shuffles + 10
// selects vs 240 shuffles.
// ---------------------------------------------------------------------------
__global__ __launch_bounds__(256) void gemv_kernel(
    const vfloat4* __restrict__ x4,  // [B][256] float4 view of x
    const float4* __restrict__ W4,   // [C][256] float4 view of W
    float* __restrict__ xw)          // [B][C]
{
    const int tid  = threadIdx.x;
    const int wave = tid >> 6;
    const int lane = tid & 63;
    const int sub  = lane >> 4;       // lane quarter 0..3
    const int row_base = blockIdx.x * 16 + wave * 4;

    float acc[4][C_CLS];
#pragma unroll
    for (int r = 0; r < 4; ++r)
#pragma unroll
        for (int c = 0; c < C_CLS; ++c) acc[r][c] = 0.0f;

#pragma unroll
    for (int p = 0; p < 4; ++p) {
        float4 w[C_CLS];
#pragma unroll
        for (int c = 0; c < C_CLS; ++c)
            w[c] = W4[c * 256 + p * 64 + lane];

#pragma unroll
        for (int r = 0; r < 4; ++r) {
            vfloat4 xv = __builtin_nontemporal_load(
                x4 + (size_t)(row_base + r) * 256 + p * 64 + lane);
#pragma unroll
            for (int c = 0; c < C_CLS; ++c) {
                acc[r][c] = fmaf(xv.x, w[c].x,
                            fmaf(xv.y, w[c].y,
                            fmaf(xv.z, w[c].z,
                            fmaf(xv.w, w[c].w, acc[r][c]))));
            }
        }
    }

    // reduction tail (verified in R3): 2 butterfly steps per row-acc,
    // quarter-pack via selects, then 4 butterfly steps on the packed reg
#pragma unroll
    for (int c = 0; c < C_CLS; ++c) {
#pragma unroll
        for (int r = 0; r < 4; ++r) {
            acc[r][c] += __shfl_xor(acc[r][c], 32, 64);
            acc[r][c] += __shfl_xor(acc[r][c], 16, 64);
        }
        float p = (sub < 2) ? (sub == 0 ? acc[0][c] : acc[1][c])
                            : (sub == 2 ? acc[2][c] : acc[3][c]);
        p += __shfl_xor(p, 8, 64);
        p += __shfl_xor(p, 4, 64);
        p += __shfl_xor(p, 2, 64);
        p += __shfl_xor(p, 1, 64);
        if ((lane & 15) == 0)
            xw[(row_base + sub) * C_CLS + c] = p;
    }
}

// ---------------------------------------------------------------------------
// Kernel 2: out[t,b,c] = coef(t) * xW[b,c]
//   coef(t) = 5 - 9*0.9^(t+1) + 4*0.8^(t+1)   (closed form of the LI scan)
// R2 structure: grid = 160 r4-chunks x 16 t-chunks; thread loads its xw
// float4 ONCE, then 16 timesteps via multiplicative coef recurrence.
// Stores: 64 lanes x 16 B = 1 KB contiguous per wave instruction.
// ---------------------------------------------------------------------------
#define T_CHUNK 16
__global__ __launch_bounds__(256) void expand_kernel(
    const float4* __restrict__ xw4,  // B*C/4 = 40960 float4
    float4* __restrict__ out4)       // T*B*C/4 float4
{
    const int SLICE4 = (B_ROWS * C_CLS) / 4;   // 40960 float4 per timestep
    const int NR     = SLICE4 / 256;           // 160 r4-chunks

    const int rblk = blockIdx.x % NR;
    const int tblk = blockIdx.x / NR;
    const int r4   = rblk * 256 + threadIdx.x;
    const int t0   = tblk * T_CHUNK;

    const float L9 = -0.15200309344504995f;    // log2(0.9)
    const float L8 = -0.32192809488736235f;    // log2(0.8)

    float4 v = xw4[r4];
    float p9 = exp2f((float)(t0 + 1) * L9);    // 0.9^(t0+1)
    float p8 = exp2f((float)(t0 + 1) * L8);    // 0.8^(t0+1)

    float4* dst = out4 + (size_t)t0 * SLICE4 + r4;
#pragma unroll
    for (int i = 0; i < T_CHUNK; ++i) {
        float coef = fmaf(-9.0f, p9, fmaf(4.0f, p8, 5.0f));
        vfloat4 o;
        o.x = v.x * coef; o.y = v.y * coef; o.z = v.z * coef; o.w = v.w * coef;
        __builtin_nontemporal_store(o, (vfloat4*)dst);
        dst += SLICE4;
        p9 *= 0.9f;
        p8 *= 0.8f;
    }
}

extern "C" void kernel_launch(void* const* d_in, const int* in_sizes, int n_in,
                              void* d_out, int out_size, void* d_ws, size_t ws_size,
                              hipStream_t stream) {
    const float* x = (const float*)d_in[0];   // [B, IN] f32
    const float* W = (const float*)d_in[1];   // [C, IN] f32
    float* out = (float*)d_out;               // [T, B, C] f32
    float* xw  = (float*)d_ws;                // [B, C] f32 scratch (655 KB)

    gemv_kernel<<<B_ROWS / 16, 256, 0, stream>>>(
        (const vfloat4*)x, (const float4*)W, xw);

    expand_kernel<<<(T_STEPS / T_CHUNK) * ((B_ROWS * C_CLS) / 4 / 256), 256, 0, stream>>>(
        (const float4*)xw, (float4*)out);
}